// Round 1
// baseline (77.579 us; speedup 1.0000x reference)
//
#include <hip/hip_runtime.h>

#define NN 8192
#define DD 128
#define BM 128
#define NTILE (NN / BM)   // 64

typedef __attribute__((ext_vector_type(8))) short bf16x8;
typedef __attribute__((ext_vector_type(4))) float f32x4;

__device__ __forceinline__ ushort f2bf(float x) {
    // RNE float -> bf16
    unsigned u = __float_as_uint(x);
    unsigned r = u + 0x7FFFu + ((u >> 16) & 1u);
    return (ushort)(r >> 16);
}

// Kernel 1: sq[i] = sum_d F[i][d]^2  (one wave per row, coalesced float2)
__global__ void sq_kernel(const float* __restrict__ F, float* __restrict__ sq) {
    int gtid = blockIdx.x * blockDim.x + threadIdx.x;
    int row  = gtid >> 6;
    int lane = threadIdx.x & 63;
    const float2 v = *(const float2*)(F + (size_t)row * DD + lane * 2);
    float s = v.x * v.x + v.y * v.y;
    #pragma unroll
    for (int off = 32; off > 0; off >>= 1) s += __shfl_down(s, off);
    if (lane == 0) sq[row] = s;
}

// Kernel 2: per 128x128 S-tile, partial = sum S_ij*(sq_i + sq_j - 2*f_i.f_j)
__global__ __launch_bounds__(256, 2) void tile_kernel(
        const float* __restrict__ F, const float* __restrict__ S,
        const float* __restrict__ sq, float* __restrict__ partials) {
    __shared__ ushort lA[BM * DD];   // bf16, XOR-swizzled rows
    __shared__ ushort lB[BM * DD];
    __shared__ float  sqi[BM];
    __shared__ float  sqj[BM];
    __shared__ float  red[4];

    const int bi = blockIdx.y, bj = blockIdx.x;
    const int gi = bi * BM, gj = bj * BM;
    const int tid = threadIdx.x;

    // ---- stage F_i, F_j tiles (fp32 -> bf16) into swizzled LDS ----
    {
        const int r0 = tid >> 5;          // 0..7
        const int c4 = (tid & 31) * 4;    // 0..124 step 4
        #pragma unroll
        for (int it = 0; it < 16; ++it) {
            const int row = it * 8 + r0;
            const float4 va = *(const float4*)(F + (size_t)(gi + row) * DD + c4);
            const float4 vb = *(const float4*)(F + (size_t)(gj + row) * DD + c4);
            int byte = row * 256 + c4 * 2;
            byte ^= (row & 7) << 4;       // bank-conflict swizzle
            *(ushort4*)((char*)lA + byte) =
                make_ushort4(f2bf(va.x), f2bf(va.y), f2bf(va.z), f2bf(va.w));
            *(ushort4*)((char*)lB + byte) =
                make_ushort4(f2bf(vb.x), f2bf(vb.y), f2bf(vb.z), f2bf(vb.w));
        }
        if (tid < 128) sqi[tid] = sq[gi + tid];
        else           sqj[tid - 128] = sq[gj + tid - 128];
    }
    __syncthreads();

    const int w  = tid >> 6;      // wave 0..3 -> rows [w*32, w*32+32)
    const int l  = tid & 63;
    const int fr = l & 15;        // fragment row (A) / col (B,D)
    const int g  = l >> 4;        // k-group
    const int wr = w * 32;

    // ---- A fragments (kept in regs) ----
    bf16x8 afrag[2][4];
    #pragma unroll
    for (int mt = 0; mt < 2; ++mt)
        #pragma unroll
        for (int kk = 0; kk < 4; ++kk) {
            const int row = wr + mt * 16 + fr;
            int byte = row * 256 + (kk * 32 + g * 8) * 2;
            byte ^= (row & 7) << 4;
            afrag[mt][kk] = *(const bf16x8*)((const char*)lA + byte);
        }

    f32x4 acc[2][8];
    #pragma unroll
    for (int mt = 0; mt < 2; ++mt)
        #pragma unroll
        for (int nt = 0; nt < 8; ++nt) acc[mt][nt] = (f32x4){0.f, 0.f, 0.f, 0.f};

    // ---- MFMA: P = F_i . F_j^T  (128x128, K=128) ----
    #pragma unroll
    for (int nt = 0; nt < 8; ++nt) {
        #pragma unroll
        for (int kk = 0; kk < 4; ++kk) {
            const int row = nt * 16 + fr;
            int byte = row * 256 + (kk * 32 + g * 8) * 2;
            byte ^= (row & 7) << 4;
            const bf16x8 bfrag = *(const bf16x8*)((const char*)lB + byte);
            acc[0][nt] = __builtin_amdgcn_mfma_f32_16x16x32_bf16(
                afrag[0][kk], bfrag, acc[0][nt], 0, 0, 0);
            acc[1][nt] = __builtin_amdgcn_mfma_f32_16x16x32_bf16(
                afrag[1][kk], bfrag, acc[1][nt], 0, 0, 0);
        }
    }

    // ---- stream S tile, accumulate S*(sq_i + sq_j - 2*P) ----
    float part = 0.f;
    float sj[8];
    #pragma unroll
    for (int nt = 0; nt < 8; ++nt) sj[nt] = sqj[nt * 16 + fr];

    #pragma unroll
    for (int mt = 0; mt < 2; ++mt) {
        #pragma unroll
        for (int r = 0; r < 4; ++r) {
            const int rowt = wr + mt * 16 + g * 4 + r;   // D-layout row
            const float si = sqi[rowt];
            const float* srow = S + (size_t)(gi + rowt) * NN + gj + fr;
            #pragma unroll
            for (int nt = 0; nt < 8; ++nt) {
                const float s = srow[nt * 16];
                part += s * (si + sj[nt] - 2.0f * acc[mt][nt][r]);
            }
        }
    }

    // ---- deterministic block reduction ----
    #pragma unroll
    for (int off = 32; off > 0; off >>= 1) part += __shfl_down(part, off);
    if (l == 0) red[w] = part;
    __syncthreads();
    if (tid == 0)
        partials[blockIdx.y * gridDim.x + blockIdx.x] = (red[0] + red[1]) + (red[2] + red[3]);
}

// Kernel 3: fixed-order final reduction of 4096 partials
__global__ void reduce_kernel(const float* __restrict__ partials, float* __restrict__ out) {
    __shared__ float sm[256];
    const int t = threadIdx.x;
    float s = 0.f;
    for (int i = t; i < NTILE * NTILE; i += 256) s += partials[i];
    sm[t] = s;
    __syncthreads();
    for (int off = 128; off > 0; off >>= 1) {
        if (t < off) sm[t] += sm[t + off];
        __syncthreads();
    }
    if (t == 0) out[0] = sm[0];
}

extern "C" void kernel_launch(void* const* d_in, const int* in_sizes, int n_in,
                              void* d_out, int out_size, void* d_ws, size_t ws_size,
                              hipStream_t stream) {
    const float* F = (const float*)d_in[0];
    const float* S = (const float*)d_in[1];
    float* ws       = (float*)d_ws;
    float* sq       = ws;            // 8192 floats
    float* partials = ws + NN;       // 4096 floats
    float* out      = (float*)d_out;

    sq_kernel<<<NN / 4, 256, 0, stream>>>(F, sq);
    dim3 grid(NTILE, NTILE);
    tile_kernel<<<grid, 256, 0, stream>>>(F, S, sq, partials);
    reduce_kernel<<<1, 256, 0, stream>>>(partials, out);
}

// Round 2
// 69.126 us; speedup vs baseline: 1.1223x; 1.1223x over previous
//
#include <hip/hip_runtime.h>

#define NN 8192
#define DD 128
#define BM 128
#define NTILE (NN / BM)   // 64

typedef __attribute__((ext_vector_type(8))) short bf16x8;
typedef __attribute__((ext_vector_type(4))) float f32x4;

__device__ __forceinline__ ushort f2bf(float x) {
    unsigned u = __float_as_uint(x);
    unsigned r = u + 0x7FFFu + ((u >> 16) & 1u);
    return (ushort)(r >> 16);
}

__device__ __forceinline__ void async16(void* lds, const void* g) {
    __builtin_amdgcn_global_load_lds(
        (const __attribute__((address_space(1))) unsigned*)g,
        (__attribute__((address_space(3))) unsigned*)lds, 16, 0, 0);
}
__device__ __forceinline__ void async4(void* lds, const void* g) {
    __builtin_amdgcn_global_load_lds(
        (const __attribute__((address_space(1))) unsigned*)g,
        (__attribute__((address_space(3))) unsigned*)lds, 4, 0, 0);
}

// Kernel 0: sq[i] = ||f_i||^2 (always); Fbf = bf16(F) (if doFbf).
__global__ void prep_kernel(const float* __restrict__ F, ushort* __restrict__ Fbf,
                            float* __restrict__ sq, int doFbf) {
    int gtid = blockIdx.x * blockDim.x + threadIdx.x;
    int row  = gtid >> 6;
    int lane = threadIdx.x & 63;
    const float2 v = *(const float2*)(F + (size_t)row * DD + lane * 2);
    if (doFbf)
        ((ushort2*)(Fbf + (size_t)row * DD))[lane] = make_ushort2(f2bf(v.x), f2bf(v.y));
    float s = v.x * v.x + v.y * v.y;
    #pragma unroll
    for (int off = 32; off > 0; off >>= 1) s += __shfl_down(s, off);
    if (lane == 0) sq[row] = s;
}

// Kernel 1: per 128x128 S-tile, partial = sum S_ij*(sq_i + sq_j - 2*f_i.f_j)
// Operand-swapped MFMA: D = F_j . F_i^T so acc regs = 4 consecutive j-columns.
template <int FAST>
__global__ __launch_bounds__(256, 2) void tile_kernel(
        const ushort* __restrict__ Fbf, const float* __restrict__ F,
        const float* __restrict__ S, const float* __restrict__ sq,
        float* __restrict__ partials) {
    __shared__ ushort lI[BM * DD];   // F_i panel (B-operand), swizzled
    __shared__ ushort lJ[BM * DD];   // F_j panel (A-operand), swizzled
    __shared__ float  sqi[BM];
    __shared__ float  sqj[BM];
    __shared__ float  red[4];

    const int bi = blockIdx.y, bj = blockIdx.x;
    const int gi = bi * BM, gj = bj * BM;
    const int tid = threadIdx.x;
    const int w = tid >> 6, l = tid & 63;

    if (FAST) {
        // ---- stage via global_load_lds: linear LDS dest, pre-swizzled global src ----
        #pragma unroll
        for (int it = 0; it < 8; ++it) {
            const int chunk = it * 4 + w;            // 1 KB chunks, 32 per panel
            const int row = chunk * 4 + (l >> 4);    // LDS row this lane lands in
            const int inb = (l & 15) * 16;           // in-row byte
            const int src = inb ^ ((row & 7) << 4);  // inverse swizzle on source
            async16((char*)lI + chunk * 1024, (const char*)(Fbf + (size_t)(gi + row) * DD) + src);
            async16((char*)lJ + chunk * 1024, (const char*)(Fbf + (size_t)(gj + row) * DD) + src);
        }
        {
            float* dstb = (w < 2 ? sqi : sqj) + (w & 1) * 64;
            const float* srcb = sq + (w < 2 ? gi : gj) + (w & 1) * 64 + l;
            async4(dstb, srcb);
        }
    } else {
        // ---- fallback: convert fp32->bf16 in-kernel (round-1 style) ----
        const int r0 = tid >> 5;
        const int c4 = (tid & 31) * 4;
        #pragma unroll
        for (int it = 0; it < 16; ++it) {
            const int row = it * 8 + r0;
            const float4 va = *(const float4*)(F + (size_t)(gi + row) * DD + c4);
            const float4 vb = *(const float4*)(F + (size_t)(gj + row) * DD + c4);
            int byte = row * 256 + c4 * 2;
            byte ^= (row & 7) << 4;
            *(ushort4*)((char*)lI + byte) =
                make_ushort4(f2bf(va.x), f2bf(va.y), f2bf(va.z), f2bf(va.w));
            *(ushort4*)((char*)lJ + byte) =
                make_ushort4(f2bf(vb.x), f2bf(vb.y), f2bf(vb.z), f2bf(vb.w));
        }
        if (tid < 128) sqi[tid] = sq[gi + tid];
        else           sqj[tid - 128] = sq[gj + tid - 128];
    }
    __syncthreads();

    const int fr = l & 15;
    const int g  = l >> 4;
    const int jw = w * 32;            // wave's j-window within the tile

    // ---- prefetch S (vectorized float4, matches acc layout) ----
    float4 sv0[8], sv1[8];
    #pragma unroll
    for (int ct = 0; ct < 8; ++ct) {
        const float* srow = S + (size_t)(gi + ct * 16 + fr) * NN + gj + jw + g * 4;
        sv0[ct] = *(const float4*)(srow);
        sv1[ct] = *(const float4*)(srow + 16);
    }

    // ---- A fragments from F_j panel ----
    bf16x8 afrag[2][4];
    #pragma unroll
    for (int kk = 0; kk < 4; ++kk) {
        {
            const int row = jw + fr;
            int byte = row * 256 + kk * 64 + g * 16;
            byte ^= (row & 7) << 4;
            afrag[0][kk] = *(const bf16x8*)((const char*)lJ + byte);
        }
        {
            const int row = jw + 16 + fr;
            int byte = row * 256 + kk * 64 + g * 16;
            byte ^= (row & 7) << 4;
            afrag[1][kk] = *(const bf16x8*)((const char*)lJ + byte);
        }
    }

    f32x4 acc[2][8];
    #pragma unroll
    for (int ct = 0; ct < 8; ++ct) {
        acc[0][ct] = (f32x4){0.f, 0.f, 0.f, 0.f};
        acc[1][ct] = (f32x4){0.f, 0.f, 0.f, 0.f};
    }

    // ---- MFMA: D = F_j . F_i^T  (S loads in flight underneath) ----
    #pragma unroll
    for (int ct = 0; ct < 8; ++ct) {
        #pragma unroll
        for (int kk = 0; kk < 4; ++kk) {
            const int row = ct * 16 + fr;
            int byte = row * 256 + kk * 64 + g * 16;
            byte ^= (row & 7) << 4;
            const bf16x8 bfrag = *(const bf16x8*)((const char*)lI + byte);
            acc[0][ct] = __builtin_amdgcn_mfma_f32_16x16x32_bf16(
                afrag[0][kk], bfrag, acc[0][ct], 0, 0, 0);
            acc[1][ct] = __builtin_amdgcn_mfma_f32_16x16x32_bf16(
                afrag[1][kk], bfrag, acc[1][ct], 0, 0, 0);
        }
    }

    // ---- consume: part += S * (sq_i + sq_j - 2*P) ----
    const float4 sj0 = *(const float4*)(sqj + jw + g * 4);
    const float4 sj1 = *(const float4*)(sqj + jw + 16 + g * 4);
    float part = 0.f;
    #pragma unroll
    for (int ct = 0; ct < 8; ++ct) {
        const float si = sqi[ct * 16 + fr];
        const float4 s0 = sv0[ct], s1 = sv1[ct];
        part += s0.x * (si + sj0.x - 2.f * acc[0][ct][0]);
        part += s0.y * (si + sj0.y - 2.f * acc[0][ct][1]);
        part += s0.z * (si + sj0.z - 2.f * acc[0][ct][2]);
        part += s0.w * (si + sj0.w - 2.f * acc[0][ct][3]);
        part += s1.x * (si + sj1.x - 2.f * acc[1][ct][0]);
        part += s1.y * (si + sj1.y - 2.f * acc[1][ct][1]);
        part += s1.z * (si + sj1.z - 2.f * acc[1][ct][2]);
        part += s1.w * (si + sj1.w - 2.f * acc[1][ct][3]);
    }

    // ---- deterministic block reduction ----
    #pragma unroll
    for (int off = 32; off > 0; off >>= 1) part += __shfl_down(part, off);
    if (l == 0) red[w] = part;
    __syncthreads();
    if (tid == 0)
        partials[blockIdx.y * gridDim.x + blockIdx.x] = (red[0] + red[1]) + (red[2] + red[3]);
}

// Kernel 2: fixed-order final reduction
__global__ void reduce_kernel(const float* __restrict__ partials, float* __restrict__ out) {
    __shared__ float sm[256];
    const int t = threadIdx.x;
    float s = 0.f;
    for (int i = t; i < NTILE * NTILE; i += 256) s += partials[i];
    sm[t] = s;
    __syncthreads();
    for (int off = 128; off > 0; off >>= 1) {
        if (t < off) sm[t] += sm[t + off];
        __syncthreads();
    }
    if (t == 0) out[0] = sm[0];
}

extern "C" void kernel_launch(void* const* d_in, const int* in_sizes, int n_in,
                              void* d_out, int out_size, void* d_ws, size_t ws_size,
                              hipStream_t stream) {
    const float* F = (const float*)d_in[0];
    const float* S = (const float*)d_in[1];
    float* sq       = (float*)d_ws;                       // 32 KB
    float* partials = sq + NN;                            // 16 KB
    ushort* Fbf     = (ushort*)((char*)d_ws + 48 * 1024); // 2 MB
    float* out      = (float*)d_out;

    const size_t need = 48 * 1024 + (size_t)NN * DD * 2 + 256;
    const int fast = (ws_size >= need) ? 1 : 0;

    prep_kernel<<<NN / 4, 256, 0, stream>>>(F, Fbf, sq, fast);
    dim3 grid(NTILE, NTILE);
    if (fast)
        tile_kernel<1><<<grid, 256, 0, stream>>>(Fbf, F, S, sq, partials);
    else
        tile_kernel<0><<<grid, 256, 0, stream>>>(Fbf, F, S, sq, partials);
    reduce_kernel<<<1, 256, 0, stream>>>(partials, out);
}